// Round 8
// baseline (228.241 us; speedup 1.0000x reference)
//
#include <hip/hip_runtime.h>
#include <hip/hip_bf16.h>
#include <stdint.h>

// Problem constants: B=4, N=M=2048, C=512, H=4, D_QK=256, D_V=128
#define SCALE_F 0.08838834764831845f  // 1/sqrt(128)

typedef __attribute__((ext_vector_type(8))) short short8;
typedef __attribute__((ext_vector_type(4))) float f32x4;
typedef __attribute__((ext_vector_type(16))) float f32x16;

__device__ __forceinline__ void g2l16(const void* g, void* l) {
  __builtin_amdgcn_global_load_lds(
      (const __attribute__((address_space(1))) void*)g,
      (__attribute__((address_space(3))) void*)l, 16, 0, 0);
}

__device__ __forceinline__ float bf2f(unsigned short s) {
  union { unsigned int i; float f; } c; c.i = ((unsigned int)s) << 16; return c.f;
}

// ---- fused prep: fp32->bf16 for x/W (blocks 0..4863) + ctx transpose/pack ---
__global__ __launch_bounds__(256) void prep(
    const float* __restrict__ x, const float* __restrict__ ctx,
    const float* __restrict__ wqkv, const float* __restrict__ wproj,
    __hip_bfloat16* __restrict__ ab, __hip_bfloat16* __restrict__ wb,
    __hip_bfloat16* __restrict__ wpb, __hip_bfloat16* __restrict__ vt)
{
  if (blockIdx.x < 4864) {
    size_t qi = (size_t)blockIdx.x * 256 + threadIdx.x;  // quad index
    const float* src; __hip_bfloat16* dst; size_t off;
    if (qi < 1048576)      { src = x;     dst = ab;  off = qi; }
    else if (qi < 1179648) { src = wqkv;  dst = wb;  off = qi - 1048576; }
    else                   { src = wproj; dst = wpb; off = qi - 1179648; }
    float4 v = ((const float4*)src)[off];
    union { __hip_bfloat16 h4[4]; uint2 u; } o;
    o.h4[0] = __float2bfloat16(v.x); o.h4[1] = __float2bfloat16(v.y);
    o.h4[2] = __float2bfloat16(v.z); o.h4[3] = __float2bfloat16(v.w);
    ((uint2*)dst)[off] = o.u;
  } else {
    __shared__ float tile[128][33];
    const int bid = blockIdx.x - 4864;   // B*H*64 = 1024
    const int mt = bid & 63;
    const int bh = bid >> 6;
    const int h = bh & 3, b = bh >> 2;
    const int tid = threadIdx.x;
    for (int i = 0; i < 16; ++i) {
      int idx = i * 256 + tid;
      int mm = idx >> 7, d = idx & 127;
      size_t gidx = ((size_t)b * 2048 + mt * 32 + mm) * 512 + h * 128 + d;
      float v = ctx[gidx];
      tile[d][mm] = v;
      ab[4194304 + gidx] = __float2bfloat16(v);  // ctx rows at ab row 8192+
    }
    __syncthreads();
    for (int i = 0; i < 16; ++i) {
      int idx = i * 256 + tid;
      int d = idx >> 5, mm = idx & 31;
      vt[((size_t)bh * 128 + d) * 2048 + mt * 32 + mm] = __float2bfloat16(tile[d][mm]);
    }
  }
}

// ---------------- NT GEMM: C[r,o] = sum_k A[r,k]*B[o,k], templated output ----
template <typename OUT>
__global__ __launch_bounds__(256) void gemm_nt(
    const __hip_bfloat16* __restrict__ A, const __hip_bfloat16* __restrict__ B,
    OUT* __restrict__ C, int O, int K, int tiles_o)
{
  __shared__ __hip_bfloat16 sA[128 * 32];
  __shared__ __hip_bfloat16 sB[128 * 32];
  const int tid = threadIdx.x;
  const int wave = tid >> 6, lane = tid & 63;
  const int ln = lane & 15, q = lane >> 4;
  const int br = (blockIdx.x / tiles_o) * 128;
  const int bo = (blockIdx.x % tiles_o) * 128;
  const int wr = (wave >> 1) * 64, wc = (wave & 1) * 64;
  const __hip_bfloat16* Ab = A + (size_t)br * K;
  const __hip_bfloat16* Bb = B + (size_t)bo * K;
  const int row0 = tid >> 2, p0 = tid & 3;
  f32x4 acc[4][4] = {};
  for (int k0 = 0; k0 < K; k0 += 32) {
    for (int i = 0; i < 2; ++i) {
      int row = i * 64 + row0;
      g2l16(Ab + (size_t)row * K + k0 + p0 * 8, (char*)sA + (i * 256 + tid) * 16);
      g2l16(Bb + (size_t)row * K + k0 + p0 * 8, (char*)sB + (i * 256 + tid) * 16);
    }
    __syncthreads();
    short8 af[4], bfr[4];
    for (int mi = 0; mi < 4; ++mi)
      af[mi] = *(const short8*)(sA + (wr + mi * 16 + ln) * 32 + q * 8);
    for (int ni = 0; ni < 4; ++ni)
      bfr[ni] = *(const short8*)(sB + (wc + ni * 16 + ln) * 32 + q * 8);
    for (int mi = 0; mi < 4; ++mi)
      for (int ni = 0; ni < 4; ++ni)
        acc[mi][ni] = __builtin_amdgcn_mfma_f32_16x16x32_bf16(af[mi], bfr[ni], acc[mi][ni], 0, 0, 0);
    __syncthreads();
  }
  for (int mi = 0; mi < 4; ++mi)
    for (int ni = 0; ni < 4; ++ni) {
      int rg = br + wr + mi * 16 + q * 4;
      int cg = bo + wc + ni * 16 + ln;
      for (int r = 0; r < 4; ++r) {
        float v = acc[mi][ni][r];
        if constexpr (sizeof(OUT) == 2)
          C[(size_t)(rg + r) * O + cg] = __float2bfloat16(v);
        else
          C[(size_t)(rg + r) * O + cg] = v;
      }
    }
}

// ---------------- l2norm + radius/scale fold, bf16 -> bf16 -------------------
__global__ __launch_bounds__(256) void normalize_qk(
    const __hip_bfloat16* __restrict__ proj, const float* __restrict__ radius,
    __hip_bfloat16* __restrict__ qn, __hip_bfloat16* __restrict__ kn)
{
  const int r = blockIdx.x;
  const int h = threadIdx.x >> 6, lane = threadIdx.x & 63;
  union { uint2 u; unsigned short s[4]; } pu;
  pu.u = *(const uint2*)(proj + (size_t)r * 1024 + h * 256 + lane * 4);
  float v0 = bf2f(pu.s[0]), v1 = bf2f(pu.s[1]), v2 = bf2f(pu.s[2]), v3 = bf2f(pu.s[3]);
  float ss = v0 * v0 + v1 * v1 + v2 * v2 + v3 * v3;
  for (int off = 1; off < 64; off <<= 1) ss += __shfl_xor(ss, off);
  float nrm = fmaxf(sqrtf(ss), 1e-12f);
  const bool isq = r < 8192;
  const int rr = isq ? r : r - 8192;
  const float rad = radius[h];
  const float sc = (isq ? rad * rad * SCALE_F : 1.0f) / nrm;
  __hip_bfloat16* dst = (isq ? qn : kn) +
      ((size_t)((rr >> 11) * 4 + h) * 2048 + (rr & 2047)) * 256 + lane * 4;
  union { __hip_bfloat16 h4[4]; uint2 u; } o;
  o.h4[0] = __float2bfloat16(v0 * sc);
  o.h4[1] = __float2bfloat16(v1 * sc);
  o.h4[2] = __float2bfloat16(v2 * sc);
  o.h4[3] = __float2bfloat16(v3 * sc);
  *(uint2*)dst = o.u;
}

// ---------------- flash attention v8: phase-staggered co-resident blocks -----
// Same per-wave work as R7 (32x32x16, 32 q-rows/wave, triple-buffered sK).
// KEY CHANGE: co-resident block pair (c, c+256) runs COMPLEMENTARY body
// orders — v0: {QK(t+1); exp(t); PV(t)}, v1: {exp(t); PV(t); QK(t+1)} — so at
// any instant one block's waves feed MFMA/LDS while the other's feed VALU,
// breaking the additive phase-locking seen in R3/R7 counters.
// grid = 512: bh(16) x nt(16) x half(2), XCD-swizzled. Partial O + denom out.
__global__ __launch_bounds__(256, 2) void attn(
    const __hip_bfloat16* __restrict__ qn,  // (bh, 2048, 256)
    const __hip_bfloat16* __restrict__ kn,  // (bh, 2048, 256)
    const __hip_bfloat16* __restrict__ vt,  // (bh, 128, 2048)
    float* __restrict__ Op,                 // (half, bh, 2048, 128) fp32
    float* __restrict__ den)                // (half, bh, 2048) fp32
{
  __shared__ __hip_bfloat16 sK[3][32 * 256];  // 3x16KB; row=512B, swz c^=(row&7)
  __shared__ __hip_bfloat16 sV[2][128 * 32];  // 2x8KB; row=64B, swz c^=((rd>>1)&3)
  __shared__ __hip_bfloat16 sP[4][32 * 40];   // per-wave P, rows padded to 40
  const int tid = threadIdx.x, wave = tid >> 6, lane = tid & 63;
  const int m32 = lane & 31, hi = lane >> 5;
  const int i = blockIdx.x;
  const int bh = (i & 7) + 8 * ((i >> 3) & 1);
  const int half = (i >> 4) & 1;
  const int nt = i >> 5;
  const int mbase = half * 1024;
  const int parity = (i >> 8) & 1;            // co-resident pair differs
  const __hip_bfloat16* Kp = kn + (size_t)bh * 2048 * 256;
  const __hip_bfloat16* Vp = vt + (size_t)bh * 128 * 2048;

  short8 qf[16];
  {
    const __hip_bfloat16* Q = qn + ((size_t)bh * 2048 + nt * 128 + wave * 32) * 256;
    for (int kk = 0; kk < 16; ++kk)
      qf[kk] = *(const short8*)(Q + m32 * 256 + kk * 16 + hi * 8);
  }

  f32x16 oacc[4];
  float denom[16];
  for (int v = 0; v < 4; ++v)
    for (int j = 0; j < 16; ++j) oacc[v][j] = 0.f;
  for (int j = 0; j < 16; ++j) denom[j] = 0.f;
  __hip_bfloat16* sPw = sP[wave];

#define STAGE_K(tile, buf)                                                   \
  for (int t = 0; t < 4; ++t) {                                              \
    int D = t * 256 + tid, row = D >> 5, cc = D & 31;                        \
    g2l16(Kp + (size_t)(mbase + (tile) * 32 + row) * 256 + ((cc ^ (row & 7)) << 3), \
          (char*)sK[buf] + D * 16);                                          \
  }
#define STAGE_V(tile, buf)                                                   \
  for (int t = 0; t < 2; ++t) {                                              \
    int D = t * 256 + tid, rd = D >> 2, cc = D & 3;                          \
    g2l16(Vp + (size_t)rd * 2048 + mbase + (tile) * 32 + ((cc ^ ((rd >> 1) & 3)) << 3), \
          (char*)sV[buf] + D * 16);                                          \
  }
#define QK_BLOCK(S, buf)                                                     \
  {                                                                          \
    const __hip_bfloat16* sKc = sK[buf];                                     \
    for (int kk = 0; kk < 16; ++kk) {                                        \
      int c = kk * 2 + hi;                                                   \
      short8 kf = *(const short8*)(sKc + m32 * 256 + ((c ^ (m32 & 7)) << 3)); \
      S = __builtin_amdgcn_mfma_f32_32x32x16_bf16(qf[kk], kf, S, 0, 0, 0);   \
    }                                                                        \
  }
#define EXP_BLOCK                                                            \
  for (int reg = 0; reg < 16; ++reg) {                                       \
    float e = __expf(S_cur[reg]);                                            \
    denom[reg] += e;                                                         \
    int row = (reg & 3) + 8 * (reg >> 2) + 4 * hi;                           \
    sPw[row * 40 + m32] = __float2bfloat16(e);                               \
  }
#define PV_BLOCK(vbuf)                                                       \
  {                                                                          \
    asm volatile("s_waitcnt lgkmcnt(0)" ::: "memory");                       \
    const __hip_bfloat16* sVc = sV[vbuf];                                    \
    for (int kc = 0; kc < 2; ++kc) {                                         \
      short8 pf = *(const short8*)(sPw + m32 * 40 + kc * 16 + hi * 8);       \
      for (int vi = 0; vi < 4; ++vi) {                                       \
        int rd = vi * 32 + m32;                                              \
        int c = kc * 2 + hi;                                                 \
        short8 vf = *(const short8*)(sVc + rd * 32 + ((c ^ ((rd >> 1) & 3)) << 3)); \
        oacc[vi] = __builtin_amdgcn_mfma_f32_32x32x16_bf16(pf, vf, oacc[vi], 0, 0, 0); \
      }                                                                      \
    }                                                                        \
  }

  // prologue: tile0 -> (K0,V0), drain; issue K1; QK(0); drain K1
  STAGE_K(0, 0);
  STAGE_V(0, 0);
  __syncthreads();
  STAGE_K(1, 1);
  f32x16 S_cur;
  for (int j = 0; j < 16; ++j) S_cur[j] = 0.f;
  QK_BLOCK(S_cur, 0);
  __syncthreads();

  if (parity == 0) {
    for (int it = 0; it < 32; ++it) {
      if (it + 2 < 32) { STAGE_K(it + 2, (it + 2) % 3); }
      if (it + 1 < 32) { STAGE_V(it + 1, (it + 1) & 1); }
      f32x16 S_next;
      for (int j = 0; j < 16; ++j) S_next[j] = 0.f;
      if (it + 1 < 32) QK_BLOCK(S_next, (it + 1) % 3);
      EXP_BLOCK;
      PV_BLOCK(it & 1);
      __syncthreads();
      S_cur = S_next;
    }
  } else {
    for (int it = 0; it < 32; ++it) {
      if (it + 2 < 32) { STAGE_K(it + 2, (it + 2) % 3); }
      if (it + 1 < 32) { STAGE_V(it + 1, (it + 1) & 1); }
      EXP_BLOCK;
      PV_BLOCK(it & 1);
      f32x16 S_next;
      for (int j = 0; j < 16; ++j) S_next[j] = 0.f;
      if (it + 1 < 32) QK_BLOCK(S_next, (it + 1) % 3);
      __syncthreads();
      S_cur = S_next;
    }
  }
#undef STAGE_K
#undef STAGE_V
#undef QK_BLOCK
#undef EXP_BLOCK
#undef PV_BLOCK

  // partial denom: reduce across the 32 ctx-col lanes
  for (int reg = 0; reg < 16; ++reg)
    for (int off = 1; off < 32; off <<= 1)
      denom[reg] += __shfl_xor(denom[reg], off);

  float* Opb = Op + ((size_t)(half * 16 + bh) * 2048 + nt * 128 + wave * 32) * 128;
  float* denb = den + (size_t)(half * 16 + bh) * 2048 + nt * 128 + wave * 32;
  for (int vi = 0; vi < 4; ++vi)
    for (int reg = 0; reg < 16; ++reg) {
      int row = (reg & 3) + 8 * (reg >> 2) + 4 * hi;
      Opb[(size_t)row * 128 + vi * 32 + m32] = oacc[vi][reg];
    }
  if (m32 == 0)
    for (int reg = 0; reg < 16; ++reg)
      denb[(reg & 3) + 8 * (reg >> 2) + 4 * hi] = denom[reg];
}

// ---------------- combine ctx halves -> bf16 ob ------------------------------
__global__ __launch_bounds__(256) void combine(
    const float* __restrict__ Op, const float* __restrict__ den,
    __hip_bfloat16* __restrict__ ob)
{
  int qi = blockIdx.x * 256 + threadIdx.x;   // 1,048,576 float4-quads
  int r = qi >> 5, dq = qi & 31;
  int bh = r >> 11, n = r & 2047, b = bh >> 2, h = bh & 3;
  float4 o0 = ((const float4*)Op)[qi];
  float4 o1 = ((const float4*)(Op + 4194304))[qi];
  float inv = 1.0f / (den[r] + den[32768 + r]);
  union { __hip_bfloat16 h4[4]; uint2 u; } o;
  o.h4[0] = __float2bfloat16((o0.x + o1.x) * inv);
  o.h4[1] = __float2bfloat16((o0.y + o1.y) * inv);
  o.h4[2] = __float2bfloat16((o0.z + o1.z) * inv);
  o.h4[3] = __float2bfloat16((o0.w + o1.w) * inv);
  *(uint2*)&ob[((size_t)b * 2048 + n) * 512 + h * 128 + dq * 4] = o.u;
}

// ---------------- launch ------------------------------------------------------
extern "C" void kernel_launch(void* const* d_in, const int* in_sizes, int n_in,
                              void* d_out, int out_size, void* d_ws, size_t ws_size,
                              hipStream_t stream) {
  const float* x      = (const float*)d_in[0];
  const float* ctx    = (const float*)d_in[1];
  const float* wqkv   = (const float*)d_in[2];
  const float* wproj  = (const float*)d_in[3];
  const float* radius = (const float*)d_in[4];
  char* ws = (char*)d_ws;
  __hip_bfloat16* ab  = (__hip_bfloat16*)(ws);              // 16 MB (x+ctx bf16)
  __hip_bfloat16* wb  = (__hip_bfloat16*)(ws + 16777216);   // 1 MB
  __hip_bfloat16* wpb = (__hip_bfloat16*)(ws + 17825792);   // 0.5 MB
  __hip_bfloat16* proj= (__hip_bfloat16*)(ws + 18350080);   // 33.5 MB bf16 (dead after normalize)
  float*          Op  = (float*)(ws + 18350080);            // 33.5 MB partial O (reuse)
  float*          den = (float*)(ws + 51904512);            // 256 KB partial denom
  __hip_bfloat16* qn  = (__hip_bfloat16*)(ws + 85458944);   // 16 MB
  __hip_bfloat16* kn  = (__hip_bfloat16*)(ws + 102236160);  // 16 MB
  __hip_bfloat16* vt  = (__hip_bfloat16*)(ws + 119013376);  // 8 MB
  __hip_bfloat16* ob  = (__hip_bfloat16*)(ws + 127401984);  // 8 MB
  float* out = (float*)d_out;

  prep<<<5888, 256, 0, stream>>>(x, ctx, wqkv, wproj, ab, wb, wpb, vt);
  gemm_nt<__hip_bfloat16><<<1024, 256, 0, stream>>>(ab, wb, proj, 1024, 512, 8);
  normalize_qk<<<16384, 256, 0, stream>>>(proj, radius, qn, kn);
  attn<<<512, 256, 0, stream>>>(qn, kn, vt, Op, den);
  combine<<<4096, 256, 0, stream>>>(Op, den, ob);
  gemm_nt<float><<<256, 256, 0, stream>>>(ob, wpb, out, 512, 512, 4);
}